// Round 1
// baseline (265.522 us; speedup 1.0000x reference)
//
#include <hip/hip_runtime.h>

// out[b,k,l,f] = x[b, src(k,l), f], B=32, L=128, F=64, K=2L=256, fp32.
//   k <  L: src = (l - k) mod L   (cyclic shift)
//   k >= L: src = (k - l) mod L   (reflected shift)
// Pure write-BW-bound broadcast: 268 MB out, 1 MB in (L2-resident).
// One thread per float4 of output (16 B/lane); all index math is shift/mask
// since L, F, 2L are powers of two.

__global__ __launch_bounds__(256) void SymmetryExpansion_kernel(
    const float4* __restrict__ x, float4* __restrict__ out) {
    // Flat float4 index over out: total = 32*256*128*16 = 16,777,216
    unsigned v = blockIdx.x * 256u + threadIdx.x;

    unsigned f4 = v & 15u;           // float4 chunk within F=64 (16 chunks)
    unsigned l  = (v >> 4) & 127u;   // l in [0,128)
    unsigned k  = (v >> 11) & 255u;  // k in [0,256)
    unsigned b  = v >> 19;           // b in [0,32)

    // src row in [0,128): both branches reduce to an add + mask (no divergence
    // cost: the ternary compiles to v_cndmask, wave-uniform within most waves
    // anyway since k varies only every 2048 threads).
    unsigned i = (k < 128u) ? ((l - k + 128u) & 127u)   // l-k can be -127..127
                            : ((k - l) & 127u);         // k-l is 1..255, >=0

    // x is (32,128,64) fp32 -> (32*128) rows of 16 float4
    out[v] = x[(((b << 7) | i) << 4) | f4];
}

extern "C" void kernel_launch(void* const* d_in, const int* in_sizes, int n_in,
                              void* d_out, int out_size, void* d_ws, size_t ws_size,
                              hipStream_t stream) {
    const float4* x = (const float4*)d_in[0];
    float4* out = (float4*)d_out;
    // total float4 elems = 32*256*128*64/4 = 16,777,216 -> 65536 blocks x 256
    dim3 grid(65536), block(256);
    hipLaunchKernelGGL(SymmetryExpansion_kernel, grid, block, 0, stream, x, out);
}

// Round 2
// 251.558 us; speedup vs baseline: 1.0555x; 1.0555x over previous
//
#include <hip/hip_runtime.h>

// out[b,k,l,f] = x[b, src(k,l), f], B=32, L=128, F=64, K=2L=256, fp32.
//   k <  L: src i = (l - k) mod L  <=>  l = (i + k) mod L   (cyclic)
//   k >= L: src i = (k - l) mod L  <=>  l = (k - i) mod L   (reflected)
//
// Round-1 gather (1 load + 1 store per thread) ran at 1 TB/s: zero per-wave
// MLP (load->waitcnt->store->retire) and 2x VMEM instr pressure.
// Round-2 MULTICAST: thread owns one source float4 (b,i,f4) and one k-chunk
// of 32; loads 16 B once, then streams 32 independent stores (fillBuffer
// pattern, which measures 6.5 TB/s on this chip).
//
// Coalescing: wave = f4 0..15 x 4 consecutive i; for fixed kk the 4 l values
// are consecutive (mod 128), so each wave store covers a contiguous 1 KiB.
//
// Grid: 32 b x 8 kchunks x 8 i_hi = 2048 blocks x 256 thr = 8 blocks/CU
// (full 32 waves/CU occupancy).

__global__ __launch_bounds__(256) void SymmetryExpansion_kernel(
    const float4* __restrict__ x, float4* __restrict__ out) {
    unsigned tid  = threadIdx.x;
    unsigned f4   = tid & 15u;        // float4 chunk within F=64
    unsigned i_lo = tid >> 4;         // 4 bits of source row

    unsigned blk  = blockIdx.x;
    unsigned i_hi = blk & 7u;         // 3 bits of source row
    unsigned kc   = (blk >> 3) & 7u;  // k-chunk: 0..3 cyclic, 4..7 reflected
    unsigned b    = blk >> 6;         // batch

    unsigned i     = (i_hi << 4) | i_lo;   // source row in [0,128)
    unsigned kbase = kc << 5;              // k in [kbase, kbase+32)

    // Both halves reduce to l = (l0 + kk) & 127:
    //   cyclic   (kbase < 128): l = (i + kbase + kk) & 127
    //   reflected(kbase >=128): l = (kbase - i + kk) & 127   (kbase - i > 0)
    unsigned l0 = ((kbase < 128u) ? (i + kbase) : (kbase - i)) & 127u;

    // x is (32,128,64) fp32 -> float4 index (b<<11)|(i<<4)|f4
    float4 v = x[(b << 11) | (i << 4) | f4];

    // out float4 index: (b<<19)|(k<<11)|(l<<4)|f4
    unsigned base = (b << 19) | (kbase << 11) | f4;
#pragma unroll
    for (unsigned kk = 0; kk < 32u; ++kk) {
        unsigned l = (l0 + kk) & 127u;
        out[base + (kk << 11) + (l << 4)] = v;
    }
}

extern "C" void kernel_launch(void* const* d_in, const int* in_sizes, int n_in,
                              void* d_out, int out_size, void* d_ws, size_t ws_size,
                              hipStream_t stream) {
    const float4* x = (const float4*)d_in[0];
    float4* out = (float4*)d_out;
    dim3 grid(2048), block(256);
    hipLaunchKernelGGL(SymmetryExpansion_kernel, grid, block, 0, stream, x, out);
}